// Round 5
// baseline (212.583 us; speedup 1.0000x reference)
//
#include <hip/hip_runtime.h>
#include <hip/hip_bf16.h>

typedef __bf16 bf16_t;
typedef __bf16 bf16x8 __attribute__((ext_vector_type(8)));
typedef float f32x4 __attribute__((ext_vector_type(4)));

#define F 128
#define KEXP 8
#define BM 64
#define STG 8192        // elems per B stage (16KB)

#define NB 196          // coarse buckets: col>>8 (256 nodes each)
#define CAP 12288       // per-bucket region capacity
#define CH 8192         // edges per binA block

// ---- init per-bucket cursors to region bases
__global__ void k_initcur(int* __restrict__ cursor){
  int t = blockIdx.x*256 + threadIdx.x;
  if (t < NB) cursor[t] = t*CAP;
}

// ---- pass A: coarse-bin edges into per-bucket regions
__global__ __launch_bounds__(256) void k_binA(const int* __restrict__ row,
    const int* __restrict__ col, int* __restrict__ cursor,
    int* __restrict__ region, int E){
  __shared__ int stage[CH];
  __shared__ unsigned char stageb[CH];
  __shared__ int hist[NB];
  __shared__ int lcur[NB];
  int tid = threadIdx.x;
  int base = blockIdx.x * CH;
  int cnt = min(CH, E - base);
  for (int i = tid; i < NB; i += 256) hist[i] = 0;
  __syncthreads();
  for (int i = tid; i < cnt; i += 256){
    int r = row[base+i], c = col[base+i];
    stage[i] = (r << 8) | (c & 255);
    stageb[i] = (unsigned char)(c >> 8);
    atomicAdd(&hist[c >> 8], 1);
  }
  __syncthreads();
  for (int i = tid; i < NB; i += 256)
    lcur[i] = atomicAdd(&cursor[i], hist[i]);
  __syncthreads();
  for (int i = tid; i < cnt; i += 256){
    int b = stageb[i];
    int pos = atomicAdd(&lcur[b], 1);
    region[pos] = stage[i];
  }
}

// ---- scan bucket counts -> global CSR bases; offs[N] = E
__global__ void k_bstart(const int* __restrict__ cursor, int* __restrict__ bstart,
                         int* __restrict__ offs, int Nn){
  __shared__ int lds[256];
  int t = threadIdx.x;
  int c = (t < NB) ? (cursor[t] - t*CAP) : 0;
  lds[t] = c; __syncthreads();
  for (int off=1; off<256; off<<=1){
    int u = (t>=off) ? lds[t-off] : 0;
    __syncthreads();
    lds[t] += u;
    __syncthreads();
  }
  if (t < NB) bstart[t] = lds[t] - c;
  if (t == NB-1){ bstart[NB] = lds[t]; offs[Nn] = lds[t]; }
}

// ---- pass B: per bucket, histogram 256 local dsts -> deg/offs, counting-sort
__global__ __launch_bounds__(256) void k_binB(const int* __restrict__ region,
    const int* __restrict__ cursor, const int* __restrict__ bstart,
    int* __restrict__ deg, int* __restrict__ offs, int* __restrict__ bucket,
    int Nn){
  __shared__ int hist[256];
  __shared__ int loff[256];
  __shared__ int lcur[256];
  int b = blockIdx.x, t = threadIdx.x;
  int cnt = cursor[b] - b*CAP;
  const int* src = region + b*CAP;
  hist[t] = 0;
  __syncthreads();
  for (int i = t; i < cnt; i += 256) atomicAdd(&hist[src[i] & 255], 1);
  __syncthreads();
  int v = hist[t];
  loff[t] = v;
  __syncthreads();
  for (int off=1; off<256; off<<=1){
    int u = (t>=off) ? loff[t-off] : 0;
    __syncthreads();
    loff[t] += u;
    __syncthreads();
  }
  int excl = loff[t] - v;
  int gb = bstart[b];
  int node = b*256 + t;
  if (node < Nn){ deg[node] = v; offs[node] = gb + excl; }
  lcur[t] = gb + excl;
  __syncthreads();
  for (int i = t; i < cnt; i += 256){
    int p = src[i];
    int pos = atomicAdd(&lcur[p & 255], 1);
    bucket[pos] = p >> 8;
  }
}

// ---- xs[n][f] = bf16( rsqrt(deg[n]) * x[n][f] )  — vectorized x8
__global__ void k_prep_xs(const float* __restrict__ x, const int* __restrict__ deg,
                          bf16_t* __restrict__ xs, int total8){
  int i = blockIdx.x*256 + threadIdx.x;
  if (i < total8){
    int n = i >> 4;
    int d = deg[n];
    float dr = d>0 ? rsqrtf((float)d) : 0.f;
    const float4 f0 = *reinterpret_cast<const float4*>(&x[i*8]);
    const float4 f1 = *reinterpret_cast<const float4*>(&x[i*8+4]);
    bf16x8 v;
    v[0]=(bf16_t)(dr*f0.x); v[1]=(bf16_t)(dr*f0.y);
    v[2]=(bf16_t)(dr*f0.z); v[3]=(bf16_t)(dr*f0.w);
    v[4]=(bf16_t)(dr*f1.x); v[5]=(bf16_t)(dr*f1.y);
    v[6]=(bf16_t)(dr*f1.z); v[7]=(bf16_t)(dr*f1.w);
    *reinterpret_cast<bf16x8*>(&xs[i*8]) = v;
  }
}

// ---- Wt: frag-linear pre-tiled B.
// stage st (0..31): h=st>>4 (hicat half), kk=(st>>1)&7 (expert), s2=st&1.
// Within stage: 16 frags (sl 0..1, cgg 0..7) x 512 elems; lane l, j:
//   f = h*128 + s2*64 + sl*32 + (l>>4)*8 + j   (hicat col; h=0 -> hi, h=1 -> x)
//   n = cgg*16 + (l&15)                        (output col)
//   src = W[kk][f][n]
__global__ void k_prep_w(const float* __restrict__ W, bf16_t* __restrict__ Wt){
  int i8 = blockIdx.x*256 + threadIdx.x;   // 32768 groups of 8 elems
  if (i8 >= 32768) return;
  int st = i8 >> 10;
  int g  = i8 & 1023;
  int frag = g >> 6;
  int lane = g & 63;
  int h = st >> 4, kk = (st >> 1) & 7, s2 = st & 1;
  int sl = frag >> 3, cgg = frag & 7;
  int n = cgg*16 + (lane & 15);
  int fbase = h*128 + s2*64 + sl*32 + (lane >> 4)*8;
  bf16x8 v;
  #pragma unroll
  for (int j=0;j<8;j++)
    v[j] = (bf16_t)W[(size_t)kk*32768 + (size_t)(fbase+j)*128 + n];
  *reinterpret_cast<bf16x8*>(&Wt[(size_t)i8*8]) = v;
}

// ---- gather-aggregate, wave-per-node: 16 lanes x bf16x8 cover one 256B row
__global__ __launch_bounds__(256) void k_agg(const bf16_t* __restrict__ xs,
    const int* __restrict__ offs, const int* __restrict__ bucket,
    bf16_t* __restrict__ hi, int Nn){
  int wid = threadIdx.x >> 6, lane = threadIdx.x & 63;
  int n = blockIdx.x*4 + wid;
  if (n >= Nn) return;
  int g = lane >> 4, j16 = lane & 15;
  int o0 = offs[n], o1 = offs[n+1];
  float acc[8] = {0.f,0.f,0.f,0.f,0.f,0.f,0.f,0.f};
  int j = o0 + g;
  for (; j + 12 < o1; j += 16){
    int r0 = bucket[j];
    int r1 = bucket[j+4];
    int r2 = bucket[j+8];
    int r3 = bucket[j+12];
    bf16x8 v0 = *reinterpret_cast<const bf16x8*>(&xs[(size_t)r0*F + j16*8]);
    bf16x8 v1 = *reinterpret_cast<const bf16x8*>(&xs[(size_t)r1*F + j16*8]);
    bf16x8 v2 = *reinterpret_cast<const bf16x8*>(&xs[(size_t)r2*F + j16*8]);
    bf16x8 v3 = *reinterpret_cast<const bf16x8*>(&xs[(size_t)r3*F + j16*8]);
    #pragma unroll
    for (int i=0;i<8;i++)
      acc[i] += ((float)v0[i] + (float)v1[i]) + ((float)v2[i] + (float)v3[i]);
  }
  for (; j < o1; j += 4){
    int r0 = bucket[j];
    bf16x8 v0 = *reinterpret_cast<const bf16x8*>(&xs[(size_t)r0*F + j16*8]);
    #pragma unroll
    for (int i=0;i<8;i++) acc[i] += (float)v0[i];
  }
  #pragma unroll
  for (int i=0;i<8;i++){
    acc[i] += __shfl_down(acc[i], 32);
    acc[i] += __shfl_down(acc[i], 16);
  }
  if (g == 0){
    int dn = o1 - o0;
    float dc = dn>0 ? rsqrtf((float)dn) : 0.f;
    bf16x8 o;
    #pragma unroll
    for (int i=0;i<8;i++) o[i] = (bf16_t)(dc*acc[i]);
    *reinterpret_cast<bf16x8*>(&hi[(size_t)n*F + j16*8]) = o;
  }
}

#define MFMA_BF16 __builtin_amdgcn_mfma_f32_16x16x32_bf16

// ---- fused gated expert GEMM, occupancy-first:
// BM=64, 256 thr = 4 waves (2 row-waves x 2 col-waves), each 32 rows x 64 cols.
// K split by hicat half (stages 0..15 from hi, 16..31 from x): A-frags per
// half only (32 VGPR), reloaded once at the boundary. Gating folds per
// expert-half (linear). B streamed through 2x16KB LDS stages, frag-linear.
__global__ __launch_bounds__(256, 3) void k_gemm(
    const bf16_t* __restrict__ hi, const float* __restrict__ x,
    const float* __restrict__ e, const bf16_t* __restrict__ Wt,
    float* __restrict__ out, int Nn)
{
  __shared__ alignas(16) bf16_t b_s[2*STG];   // 32KB
  __shared__ float e_s[BM*KEXP];              // 2KB
  int tid = threadIdx.x;
  int base = blockIdx.x * BM;
  int lane = tid & 63, wid = tid >> 6;
  int rw = wid >> 1, cw = wid & 1;
  int r16 = lane & 15, kc = lane >> 4;

  // stage e gates
  if (tid < 128){
    int row = tid >> 1;
    int srow = min(base + row, Nn-1);
    *reinterpret_cast<float4*>(&e_s[tid*4]) =
      *reinterpret_cast<const float4*>(&e[(size_t)srow*KEXP + (tid&1)*4]);
  }

  // A-frags, half 0 (hi): rows rw*32 + rg*16 + r16, cols fi*32 + kc*8
  int rA = min(base + rw*32 + r16,      Nn-1);
  int rB = min(base + rw*32 + 16 + r16, Nn-1);
  bf16x8 a[2][4];
  #pragma unroll
  for (int fi=0; fi<4; fi++){
    a[0][fi] = *reinterpret_cast<const bf16x8*>(&hi[(size_t)rA*F + fi*32 + kc*8]);
    a[1][fi] = *reinterpret_cast<const bf16x8*>(&hi[(size_t)rB*F + fi*32 + kc*8]);
  }

  // prologue: stage 0 -> dbuf0
  int4 breg[4];
  #pragma unroll
  for (int i=0;i<4;i++)
    breg[i] = *reinterpret_cast<const int4*>(&Wt[(size_t)(i*256+tid)*8]);
  #pragma unroll
  for (int i=0;i<4;i++)
    *reinterpret_cast<int4*>(&b_s[(i*256+tid)*8]) = breg[i];
  __syncthreads();

  f32x4 acc[2][4], ck[2][4];
  #pragma unroll
  for (int rg=0;rg<2;rg++)
    #pragma unroll
    for (int cg=0;cg<4;cg++){
      acc[rg][cg] = (f32x4){0.f,0.f,0.f,0.f};
      ck[rg][cg]  = (f32x4){0.f,0.f,0.f,0.f};
    }

  for (int sp=0; sp<16; sp++){
    if (sp == 8){
      // half boundary: reload A-frags from x (f32 -> bf16)
      #pragma unroll
      for (int fi=0; fi<4; fi++){
        const float4 f0 = *reinterpret_cast<const float4*>(&x[(size_t)rA*F + fi*32 + kc*8]);
        const float4 f1 = *reinterpret_cast<const float4*>(&x[(size_t)rA*F + fi*32 + kc*8 + 4]);
        bf16x8 v;
        v[0]=(bf16_t)f0.x; v[1]=(bf16_t)f0.y; v[2]=(bf16_t)f0.z; v[3]=(bf16_t)f0.w;
        v[4]=(bf16_t)f1.x; v[5]=(bf16_t)f1.y; v[6]=(bf16_t)f1.z; v[7]=(bf16_t)f1.w;
        a[0][fi] = v;
        const float4 g0 = *reinterpret_cast<const float4*>(&x[(size_t)rB*F + fi*32 + kc*8]);
        const float4 g1 = *reinterpret_cast<const float4*>(&x[(size_t)rB*F + fi*32 + kc*8 + 4]);
        bf16x8 u;
        u[0]=(bf16_t)g0.x; u[1]=(bf16_t)g0.y; u[2]=(bf16_t)g0.z; u[3]=(bf16_t)g0.w;
        u[4]=(bf16_t)g1.x; u[5]=(bf16_t)g1.y; u[6]=(bf16_t)g1.z; u[7]=(bf16_t)g1.w;
        a[1][fi] = u;
      }
    }

    // ---- half A (st = 2sp, s2=0): read dbuf0, prefetch st+1 -> dbuf1
    {
      const bf16_t* wsrc = Wt + (size_t)(2*sp+1)*STG;
      #pragma unroll
      for (int i=0;i<4;i++)
        breg[i] = *reinterpret_cast<const int4*>(&wsrc[(size_t)(i*256+tid)*8]);
      #pragma unroll
      for (int sl=0; sl<2; sl++){
        #pragma unroll
        for (int cg=0; cg<4; cg++){
          bf16x8 b = *reinterpret_cast<const bf16x8*>(
              &b_s[(sl*8 + cw*4 + cg)*512 + lane*8]);
          ck[0][cg] = MFMA_BF16(a[0][sl], b, ck[0][cg], 0, 0, 0);
          ck[1][cg] = MFMA_BF16(a[1][sl], b, ck[1][cg], 0, 0, 0);
        }
      }
      #pragma unroll
      for (int i=0;i<4;i++)
        *reinterpret_cast<int4*>(&b_s[STG + (i*256+tid)*8]) = breg[i];
      __syncthreads();
    }

    // ---- half B (st = 2sp+1, s2=1): read dbuf1, prefetch st+2 -> dbuf0, fold
    {
      if (sp < 15){
        const bf16_t* wsrc = Wt + (size_t)(2*sp+2)*STG;
        #pragma unroll
        for (int i=0;i<4;i++)
          breg[i] = *reinterpret_cast<const int4*>(&wsrc[(size_t)(i*256+tid)*8]);
      }
      #pragma unroll
      for (int sl=0; sl<2; sl++){
        #pragma unroll
        for (int cg=0; cg<4; cg++){
          bf16x8 b = *reinterpret_cast<const bf16x8*>(
              &b_s[STG + (sl*8 + cw*4 + cg)*512 + lane*8]);
          ck[0][cg] = MFMA_BF16(a[0][2+sl], b, ck[0][cg], 0, 0, 0);
          ck[1][cg] = MFMA_BF16(a[1][2+sl], b, ck[1][cg], 0, 0, 0);
        }
      }
      // fold expert kk for this half
      int kk = sp & 7;
      float ev[2][4];
      #pragma unroll
      for (int rg=0;rg<2;rg++)
        #pragma unroll
        for (int r=0;r<4;r++)
          ev[rg][r] = e_s[(rw*32 + rg*16 + kc*4 + r)*KEXP + kk];
      #pragma unroll
      for (int rg=0;rg<2;rg++)
        #pragma unroll
        for (int cg=0;cg<4;cg++){
          #pragma unroll
          for (int r=0;r<4;r++)
            acc[rg][cg][r] += ev[rg][r]*ck[rg][cg][r];
          ck[rg][cg] = (f32x4){0.f,0.f,0.f,0.f};
        }
      if (sp < 15){
        #pragma unroll
        for (int i=0;i<4;i++)
          *reinterpret_cast<int4*>(&b_s[(i*256+tid)*8]) = breg[i];
      }
      __syncthreads();
    }
  }

  // epilogue: + residual
  #pragma unroll
  for (int rg=0;rg<2;rg++){
    #pragma unroll
    for (int cg=0; cg<4; cg++){
      int ocol = cw*64 + cg*16 + r16;
      #pragma unroll
      for (int r=0; r<4; r++){
        int node = base + rw*32 + rg*16 + kc*4 + r;
        if (node < Nn)
          out[(size_t)node*F + ocol] = acc[rg][cg][r] + x[(size_t)node*F + ocol];
      }
    }
  }
}

extern "C" void kernel_launch(void* const* d_in, const int* in_sizes, int n_in,
                              void* d_out, int out_size, void* d_ws, size_t ws_size,
                              hipStream_t stream){
  const float* x  = (const float*)d_in[0];
  const int*  adj = (const int*)d_in[1];
  const float* e  = (const float*)d_in[2];
  const float* W  = (const float*)d_in[3];
  float* out = (float*)d_out;
  int Nn = in_sizes[0] / F;     // 50000
  int E  = in_sizes[1] / 2;     // 1600000
  const int* rowp = adj;
  const int* colp = adj + E;

  char* w = (char*)d_ws;
  auto alloc = [&](size_t b){ char* p = w; w += (b + 255) & ~(size_t)255; return p; };
  int* deg     = (int*)alloc((size_t)Nn*4);
  int* offs    = (int*)alloc(((size_t)Nn+1)*4);
  int* cursor  = (int*)alloc((size_t)NB*4);
  int* bstart  = (int*)alloc((size_t)(NB+1)*4);
  int* bucket  = (int*)alloc((size_t)E*4);
  char* uni    = alloc((size_t)Nn*F*2 > (size_t)NB*CAP*4 ? (size_t)Nn*F*2
                                                          : (size_t)NB*CAP*4);
  int* region  = (int*)uni;      // dead after k_binB
  bf16_t* xs   = (bf16_t*)uni;   // live from k_prep_xs
  bf16_t* hi   = (bf16_t*)alloc((size_t)Nn*F*2);
  bf16_t* Wt   = (bf16_t*)alloc((size_t)2048*F*2);

  int nchunks = (E + CH - 1) / CH;
  k_initcur<<<1, 256, 0, stream>>>(cursor);
  k_binA<<<nchunks, 256, 0, stream>>>(rowp, colp, cursor, region, E);
  k_bstart<<<1, 256, 0, stream>>>(cursor, bstart, offs, Nn);
  k_binB<<<NB, 256, 0, stream>>>(region, cursor, bstart, deg, offs, bucket, Nn);
  k_prep_xs<<<(Nn*F/8+255)/256, 256, 0, stream>>>(x, deg, xs, Nn*F/8);
  k_prep_w<<<(32768+255)/256, 256, 0, stream>>>(W, Wt);
  k_agg<<<(Nn+3)/4, 256, 0, stream>>>(xs, offs, bucket, hi, Nn);
  k_gemm<<<(Nn+BM-1)/BM, 256, 0, stream>>>(hi, x, e, Wt, out, Nn);
}

// Round 6
// 165.130 us; speedup vs baseline: 1.2874x; 1.2874x over previous
//
#include <hip/hip_runtime.h>
#include <hip/hip_bf16.h>

typedef __bf16 bf16_t;
typedef __bf16 bf16x8 __attribute__((ext_vector_type(8)));
typedef float f32x4 __attribute__((ext_vector_type(4)));

#define F 128
#define KEXP 8
#define BM 64
#define STG 8192        // elems per B stage

#define NB 196          // coarse buckets: col>>8 (256 nodes each)
#define CAP 12288       // per-bucket region capacity
#define CH 8192         // edges per binA block

// ---- init per-bucket cursors to region bases
__global__ void k_initcur(int* __restrict__ cursor){
  int t = blockIdx.x*256 + threadIdx.x;
  if (t < NB) cursor[t] = t*CAP;
}

// ---- pass A: coarse-bin edges into per-bucket regions
__global__ __launch_bounds__(256) void k_binA(const int* __restrict__ row,
    const int* __restrict__ col, int* __restrict__ cursor,
    int* __restrict__ region, int E){
  __shared__ int stage[CH];
  __shared__ unsigned char stageb[CH];
  __shared__ int hist[NB];
  __shared__ int lcur[NB];
  int tid = threadIdx.x;
  int base = blockIdx.x * CH;
  int cnt = min(CH, E - base);
  for (int i = tid; i < NB; i += 256) hist[i] = 0;
  __syncthreads();
  for (int i = tid; i < cnt; i += 256){
    int r = row[base+i], c = col[base+i];
    stage[i] = (r << 8) | (c & 255);
    stageb[i] = (unsigned char)(c >> 8);
    atomicAdd(&hist[c >> 8], 1);
  }
  __syncthreads();
  for (int i = tid; i < NB; i += 256)
    lcur[i] = atomicAdd(&cursor[i], hist[i]);
  __syncthreads();
  for (int i = tid; i < cnt; i += 256){
    int b = stageb[i];
    int pos = atomicAdd(&lcur[b], 1);
    region[pos] = stage[i];
  }
}

// ---- scan bucket counts -> global CSR bases; offs[N] = E
__global__ void k_bstart(const int* __restrict__ cursor, int* __restrict__ bstart,
                         int* __restrict__ offs, int Nn){
  __shared__ int lds[256];
  int t = threadIdx.x;
  int c = (t < NB) ? (cursor[t] - t*CAP) : 0;
  lds[t] = c; __syncthreads();
  for (int off=1; off<256; off<<=1){
    int u = (t>=off) ? lds[t-off] : 0;
    __syncthreads();
    lds[t] += u;
    __syncthreads();
  }
  if (t < NB) bstart[t] = lds[t] - c;
  if (t == NB-1){ bstart[NB] = lds[t]; offs[Nn] = lds[t]; }
}

// ---- pass B: per bucket, histogram 256 local dsts -> deg/offs, counting-sort
__global__ __launch_bounds__(256) void k_binB(const int* __restrict__ region,
    const int* __restrict__ cursor, const int* __restrict__ bstart,
    int* __restrict__ deg, int* __restrict__ offs, int* __restrict__ bucket,
    int Nn){
  __shared__ int hist[256];
  __shared__ int loff[256];
  __shared__ int lcur[256];
  int b = blockIdx.x, t = threadIdx.x;
  int cnt = cursor[b] - b*CAP;
  const int* src = region + b*CAP;
  hist[t] = 0;
  __syncthreads();
  for (int i = t; i < cnt; i += 256) atomicAdd(&hist[src[i] & 255], 1);
  __syncthreads();
  int v = hist[t];
  loff[t] = v;
  __syncthreads();
  for (int off=1; off<256; off<<=1){
    int u = (t>=off) ? loff[t-off] : 0;
    __syncthreads();
    loff[t] += u;
    __syncthreads();
  }
  int excl = loff[t] - v;
  int gb = bstart[b];
  int node = b*256 + t;
  if (node < Nn){ deg[node] = v; offs[node] = gb + excl; }
  lcur[t] = gb + excl;
  __syncthreads();
  for (int i = t; i < cnt; i += 256){
    int p = src[i];
    int pos = atomicAdd(&lcur[p & 255], 1);
    bucket[pos] = p >> 8;
  }
}

// ---- xs[n][f] = bf16( rsqrt(deg[n]) * x[n][f] )  — vectorized x8
__global__ void k_prep_xs(const float* __restrict__ x, const int* __restrict__ deg,
                          bf16_t* __restrict__ xs, int total8){
  int i = blockIdx.x*256 + threadIdx.x;
  if (i < total8){
    int n = i >> 4;
    int d = deg[n];
    float dr = d>0 ? rsqrtf((float)d) : 0.f;
    const float4 f0 = *reinterpret_cast<const float4*>(&x[i*8]);
    const float4 f1 = *reinterpret_cast<const float4*>(&x[i*8+4]);
    bf16x8 v;
    v[0]=(bf16_t)(dr*f0.x); v[1]=(bf16_t)(dr*f0.y);
    v[2]=(bf16_t)(dr*f0.z); v[3]=(bf16_t)(dr*f0.w);
    v[4]=(bf16_t)(dr*f1.x); v[5]=(bf16_t)(dr*f1.y);
    v[6]=(bf16_t)(dr*f1.z); v[7]=(bf16_t)(dr*f1.w);
    *reinterpret_cast<bf16x8*>(&xs[i*8]) = v;
  }
}

// ---- Wt: frag-linear pre-tiled B (same layout as r5).
// stage st (0..31): h=st>>4 (hicat half), kk=(st>>1)&7 (expert), s2=st&1.
// frag = sl*8 + cgg (sl 0..1, cgg 0..7), 512 elems each; lane l, j:
//   f = h*128 + s2*64 + sl*32 + (l>>4)*8 + j   (hicat col)
//   n = cgg*16 + (l&15)                        (output col)
__global__ void k_prep_w(const float* __restrict__ W, bf16_t* __restrict__ Wt){
  int i8 = blockIdx.x*256 + threadIdx.x;   // 32768 groups of 8 elems
  if (i8 >= 32768) return;
  int st = i8 >> 10;
  int g  = i8 & 1023;
  int frag = g >> 6;
  int lane = g & 63;
  int h = st >> 4, kk = (st >> 1) & 7, s2 = st & 1;
  int sl = frag >> 3, cgg = frag & 7;
  int n = cgg*16 + (lane & 15);
  int fbase = h*128 + s2*64 + sl*32 + (lane >> 4)*8;
  bf16x8 v;
  #pragma unroll
  for (int j=0;j<8;j++)
    v[j] = (bf16_t)W[(size_t)kk*32768 + (size_t)(fbase+j)*128 + n];
  *reinterpret_cast<bf16x8*>(&Wt[(size_t)i8*8]) = v;
}

// ---- gather-aggregate, wave-per-node: 16 lanes x bf16x8 cover one 256B row
__global__ __launch_bounds__(256) void k_agg(const bf16_t* __restrict__ xs,
    const int* __restrict__ offs, const int* __restrict__ bucket,
    bf16_t* __restrict__ hi, int Nn){
  int wid = threadIdx.x >> 6, lane = threadIdx.x & 63;
  int n = blockIdx.x*4 + wid;
  if (n >= Nn) return;
  int g = lane >> 4, j16 = lane & 15;
  int o0 = offs[n], o1 = offs[n+1];
  float acc[8] = {0.f,0.f,0.f,0.f,0.f,0.f,0.f,0.f};
  int j = o0 + g;
  for (; j + 12 < o1; j += 16){
    int r0 = bucket[j];
    int r1 = bucket[j+4];
    int r2 = bucket[j+8];
    int r3 = bucket[j+12];
    bf16x8 v0 = *reinterpret_cast<const bf16x8*>(&xs[(size_t)r0*F + j16*8]);
    bf16x8 v1 = *reinterpret_cast<const bf16x8*>(&xs[(size_t)r1*F + j16*8]);
    bf16x8 v2 = *reinterpret_cast<const bf16x8*>(&xs[(size_t)r2*F + j16*8]);
    bf16x8 v3 = *reinterpret_cast<const bf16x8*>(&xs[(size_t)r3*F + j16*8]);
    #pragma unroll
    for (int i=0;i<8;i++)
      acc[i] += ((float)v0[i] + (float)v1[i]) + ((float)v2[i] + (float)v3[i]);
  }
  for (; j < o1; j += 4){
    int r0 = bucket[j];
    bf16x8 v0 = *reinterpret_cast<const bf16x8*>(&xs[(size_t)r0*F + j16*8]);
    #pragma unroll
    for (int i=0;i<8;i++) acc[i] += (float)v0[i];
  }
  #pragma unroll
  for (int i=0;i<8;i++){
    acc[i] += __shfl_down(acc[i], 32);
    acc[i] += __shfl_down(acc[i], 16);
  }
  if (g == 0){
    int dn = o1 - o0;
    float dc = dn>0 ? rsqrtf((float)dn) : 0.f;
    bf16x8 o;
    #pragma unroll
    for (int i=0;i<8;i++) o[i] = (bf16_t)(dc*acc[i]);
    *reinterpret_cast<bf16x8*>(&hi[(size_t)n*F + j16*8]) = o;
  }
}

#define MFMA_BF16 __builtin_amdgcn_mfma_f32_16x16x32_bf16

// ---- fused gated expert GEMM, barrier-free:
// BM=64, 4 waves = 2 row-waves x 2 col-waves, 32 rows x 64 cols each.
// B-frags streamed DIRECTLY global->VGPR from frag-linear Wt (L2-resident,
// lane reads its own 16B -> coalesced 1KB/instr). No LDS staging, no
// __syncthreads in the K loop -> waves independent, latency hidden by
// wave-level overlap. Double-buffered B regs (one stage ahead).
__global__ __launch_bounds__(256) void k_gemm(
    const bf16_t* __restrict__ hi, const float* __restrict__ x,
    const float* __restrict__ e, const bf16_t* __restrict__ Wt,
    float* __restrict__ out, int Nn)
{
  __shared__ float e_s[BM*KEXP];              // 2KB, staged once
  int tid = threadIdx.x;
  int base = blockIdx.x * BM;
  int lane = tid & 63, wid = tid >> 6;
  int rw = wid >> 1, cw = wid & 1;
  int r16 = lane & 15, kc = lane >> 4;

  if (tid < 128){
    int row = tid >> 1;
    int srow = min(base + row, Nn-1);
    *reinterpret_cast<float4*>(&e_s[tid*4]) =
      *reinterpret_cast<const float4*>(&e[(size_t)srow*KEXP + (tid&1)*4]);
  }

  // A-frags, half 0 (hi): rows rw*32 {+16}, cols fi*32 + kc*8
  int rA = min(base + rw*32 + r16,      Nn-1);
  int rB = min(base + rw*32 + 16 + r16, Nn-1);
  bf16x8 a[2][4];
  #pragma unroll
  for (int fi=0; fi<4; fi++){
    a[0][fi] = *reinterpret_cast<const bf16x8*>(&hi[(size_t)rA*F + fi*32 + kc*8]);
    a[1][fi] = *reinterpret_cast<const bf16x8*>(&hi[(size_t)rB*F + fi*32 + kc*8]);
  }

  // per-wave B-frag pointers: frag (sl, cg) at Wt[st*STG + (sl*8+cw*4+cg)*512 + lane*8]
  const bf16_t* wbase = Wt + (size_t)(cw*4)*512 + (size_t)lane*8;
  // prologue: stage 0 -> bc
  bf16x8 bc[2][4], bn[2][4];
  #pragma unroll
  for (int sl=0; sl<2; sl++)
    #pragma unroll
    for (int cg=0; cg<4; cg++)
      bc[sl][cg] = *reinterpret_cast<const bf16x8*>(&wbase[(size_t)(sl*8+cg)*512]);

  __syncthreads();   // e_s ready (only barrier in the kernel)

  f32x4 acc[2][4], ck[2][4];
  #pragma unroll
  for (int rg=0;rg<2;rg++)
    #pragma unroll
    for (int cg=0;cg<4;cg++){
      acc[rg][cg] = (f32x4){0.f,0.f,0.f,0.f};
      ck[rg][cg]  = (f32x4){0.f,0.f,0.f,0.f};
    }

  for (int sp=0; sp<16; sp++){
    if (sp == 8){
      // half boundary: reload A-frags from x (f32 -> bf16)
      #pragma unroll
      for (int fi=0; fi<4; fi++){
        const float4 f0 = *reinterpret_cast<const float4*>(&x[(size_t)rA*F + fi*32 + kc*8]);
        const float4 f1 = *reinterpret_cast<const float4*>(&x[(size_t)rA*F + fi*32 + kc*8 + 4]);
        bf16x8 v;
        v[0]=(bf16_t)f0.x; v[1]=(bf16_t)f0.y; v[2]=(bf16_t)f0.z; v[3]=(bf16_t)f0.w;
        v[4]=(bf16_t)f1.x; v[5]=(bf16_t)f1.y; v[6]=(bf16_t)f1.z; v[7]=(bf16_t)f1.w;
        a[0][fi] = v;
        const float4 g0 = *reinterpret_cast<const float4*>(&x[(size_t)rB*F + fi*32 + kc*8]);
        const float4 g1 = *reinterpret_cast<const float4*>(&x[(size_t)rB*F + fi*32 + kc*8 + 4]);
        bf16x8 u;
        u[0]=(bf16_t)g0.x; u[1]=(bf16_t)g0.y; u[2]=(bf16_t)g0.z; u[3]=(bf16_t)g0.w;
        u[4]=(bf16_t)g1.x; u[5]=(bf16_t)g1.y; u[6]=(bf16_t)g1.z; u[7]=(bf16_t)g1.w;
        a[1][fi] = u;
      }
    }

    // stage 2sp in bc; prefetch 2sp+1 -> bn, MFMA bc
    {
      const bf16_t* wn = wbase + (size_t)(2*sp+1)*STG;
      #pragma unroll
      for (int sl=0; sl<2; sl++)
        #pragma unroll
        for (int cg=0; cg<4; cg++)
          bn[sl][cg] = *reinterpret_cast<const bf16x8*>(&wn[(size_t)(sl*8+cg)*512]);
      #pragma unroll
      for (int sl=0; sl<2; sl++)
        #pragma unroll
        for (int cg=0; cg<4; cg++){
          ck[0][cg] = MFMA_BF16(a[0][sl], bc[sl][cg], ck[0][cg], 0, 0, 0);
          ck[1][cg] = MFMA_BF16(a[1][sl], bc[sl][cg], ck[1][cg], 0, 0, 0);
        }
    }
    // stage 2sp+1 in bn; prefetch 2sp+2 -> bc, MFMA bn, fold expert
    {
      if (sp < 15){
        const bf16_t* wn = wbase + (size_t)(2*sp+2)*STG;
        #pragma unroll
        for (int sl=0; sl<2; sl++)
          #pragma unroll
          for (int cg=0; cg<4; cg++)
            bc[sl][cg] = *reinterpret_cast<const bf16x8*>(&wn[(size_t)(sl*8+cg)*512]);
      }
      #pragma unroll
      for (int sl=0; sl<2; sl++)
        #pragma unroll
        for (int cg=0; cg<4; cg++){
          ck[0][cg] = MFMA_BF16(a[0][2+sl], bn[sl][cg], ck[0][cg], 0, 0, 0);
          ck[1][cg] = MFMA_BF16(a[1][2+sl], bn[sl][cg], ck[1][cg], 0, 0, 0);
        }
      int kk = sp & 7;
      float ev[2][4];
      #pragma unroll
      for (int rg=0;rg<2;rg++)
        #pragma unroll
        for (int r=0;r<4;r++)
          ev[rg][r] = e_s[(rw*32 + rg*16 + kc*4 + r)*KEXP + kk];
      #pragma unroll
      for (int rg=0;rg<2;rg++)
        #pragma unroll
        for (int cg=0;cg<4;cg++){
          #pragma unroll
          for (int r=0;r<4;r++)
            acc[rg][cg][r] += ev[rg][r]*ck[rg][cg][r];
          ck[rg][cg] = (f32x4){0.f,0.f,0.f,0.f};
        }
    }
  }

  // epilogue: + residual
  #pragma unroll
  for (int rg=0;rg<2;rg++){
    #pragma unroll
    for (int cg=0; cg<4; cg++){
      int ocol = cw*64 + cg*16 + r16;
      #pragma unroll
      for (int r=0; r<4; r++){
        int node = base + rw*32 + rg*16 + kc*4 + r;
        if (node < Nn)
          out[(size_t)node*F + ocol] = acc[rg][cg][r] + x[(size_t)node*F + ocol];
      }
    }
  }
}

extern "C" void kernel_launch(void* const* d_in, const int* in_sizes, int n_in,
                              void* d_out, int out_size, void* d_ws, size_t ws_size,
                              hipStream_t stream){
  const float* x  = (const float*)d_in[0];
  const int*  adj = (const int*)d_in[1];
  const float* e  = (const float*)d_in[2];
  const float* W  = (const float*)d_in[3];
  float* out = (float*)d_out;
  int Nn = in_sizes[0] / F;     // 50000
  int E  = in_sizes[1] / 2;     // 1600000
  const int* rowp = adj;
  const int* colp = adj + E;

  char* w = (char*)d_ws;
  auto alloc = [&](size_t b){ char* p = w; w += (b + 255) & ~(size_t)255; return p; };
  int* deg     = (int*)alloc((size_t)Nn*4);
  int* offs    = (int*)alloc(((size_t)Nn+1)*4);
  int* cursor  = (int*)alloc((size_t)NB*4);
  int* bstart  = (int*)alloc((size_t)(NB+1)*4);
  int* bucket  = (int*)alloc((size_t)E*4);
  char* uni    = alloc((size_t)Nn*F*2 > (size_t)NB*CAP*4 ? (size_t)Nn*F*2
                                                          : (size_t)NB*CAP*4);
  int* region  = (int*)uni;      // dead after k_binB
  bf16_t* xs   = (bf16_t*)uni;   // live from k_prep_xs
  bf16_t* hi   = (bf16_t*)alloc((size_t)Nn*F*2);
  bf16_t* Wt   = (bf16_t*)alloc((size_t)2048*F*2);

  int nchunks = (E + CH - 1) / CH;
  k_initcur<<<1, 256, 0, stream>>>(cursor);
  k_binA<<<nchunks, 256, 0, stream>>>(rowp, colp, cursor, region, E);
  k_bstart<<<1, 256, 0, stream>>>(cursor, bstart, offs, Nn);
  k_binB<<<NB, 256, 0, stream>>>(region, cursor, bstart, deg, offs, bucket, Nn);
  k_prep_xs<<<(Nn*F/8+255)/256, 256, 0, stream>>>(x, deg, xs, Nn*F/8);
  k_prep_w<<<(32768+255)/256, 256, 0, stream>>>(W, Wt);
  k_agg<<<(Nn+3)/4, 256, 0, stream>>>(xs, offs, bucket, hi, Nn);
  k_gemm<<<(Nn+BM-1)/BM, 256, 0, stream>>>(hi, x, e, Wt, out, Nn);
}